// Round 15
// baseline (130.352 us; speedup 1.0000x reference)
//
#include <hip/hip_runtime.h>
#include <hip/hip_bf16.h>

typedef __attribute__((ext_vector_type(8))) short bf16x8;
typedef __attribute__((ext_vector_type(4))) float f32x4;
typedef __attribute__((ext_vector_type(16))) float f32x16;

#define DM   1024
#define SEQ  2048
#define NB   2
#define NH   16
#define MR   (NB*SEQ)            /* 4096 rows of the flattened [B*S, D] matrices */

#define SMK  (MR*DM)             /* 4194304 elements per [4096,1024] tensor */
#define W1M  (DM*DM)             /* 1048576 elements per weight matrix */

/* 0.125 * log2(e): folded into Q projection so attention uses exp2 directly */
#define QSCALE 0.18033688011112042f

/* workspace layout, in bf16 (ushort) units. concat aliases OFF_QB. */
#define OFF_QB  ((size_t)0)
#define OFF_WO  ((size_t)(3*(size_t)SMK + 3*(size_t)W1M))
#define OFF_QP  ((size_t)(3*(size_t)SMK + 4*(size_t)W1M))
#define OFF_KP  ((size_t)(4*(size_t)SMK + 4*(size_t)W1M))
#define OFF_VP  ((size_t)(5*(size_t)SMK + 4*(size_t)W1M))       /* V^T: [DM][MR] */
#define OFF_CC  ((size_t)0)

__device__ __forceinline__ unsigned short f2bf(float f) {
  union { __hip_bfloat16 b; unsigned short u; } cv;
  cv.b = __float2bfloat16(f);
  return cv.u;
}

/* v_cvt_pk_bf16_f32: packs (lo,hi) floats into one u32 of 2 bf16 */
__device__ __forceinline__ unsigned int cvtpk_bf16(float lo, float hi) {
  unsigned int r;
  asm("v_cvt_pk_bf16_f32 %0, %1, %2" : "=v"(r) : "v"(lo), "v"(hi));
  return r;
}

/* v_permlane32_swap_b32: a.upper32lanes <-> b.lower32lanes (both results used) */
__device__ __forceinline__ void plane32_swap(unsigned int& a, unsigned int& b) {
  asm("v_permlane32_swap_b32 %0, %1" : "+v"(a), "+v"(b));
}

/* ---------------- Wo f32 -> bf16 ---------------- */
__global__ __launch_bounds__(256) void cvt_wo(const float* __restrict__ wo,
                                              unsigned short* __restrict__ dst) {
  int i = blockIdx.x * 256 + threadIdx.x;      /* W1M/4 threads */
  float4 v = reinterpret_cast<const float4*>(wo)[i];
  ushort4 o;
  o.x = f2bf(v.x); o.y = f2bf(v.y); o.z = f2bf(v.z); o.w = f2bf(v.w);
  reinterpret_cast<ushort4*>(dst)[i] = o;
}

/* ---------------- async global->LDS, 16B per lane ---------------- */
__device__ __forceinline__ void gload_lds16(const void* g, void* l) {
  __builtin_amdgcn_global_load_lds(
      (const __attribute__((address_space(1))) unsigned int*)g,
      (__attribute__((address_space(3))) unsigned int*)l,
      16, 0, 0);
}

/* ---------------- f32-input 128x64 GEMM body: C = (A*B^T + bias)*scale ------------
 * Small tile -> 1536 blocks = ~6/CU: latency hiding via TLP (R14 lesson: depth
 * costs occupancy, breadth wins). R13's proven 2-LDS-buffer pipeline: loads for
 * tile kt+2 issued at kt, committed (cvt_pk + ds_write) at kt+1, consumed at kt+2.
 * Raw s_barrier + lgkmcnt(0) only — staging loads stay in flight across barriers. */
template<bool BIAS_ROW>
__device__ __forceinline__ void gemm_f32_body(unsigned short* __restrict__ As,
                                              unsigned short* __restrict__ Bs,
                                              const float* __restrict__ A,
                                              const float* __restrict__ B,
                                              const float* __restrict__ bias,
                                              unsigned short* __restrict__ C,
                                              int N, int K, float scale,
                                              int brow, int bcol) {
  const int tid  = threadIdx.x;
  const int lane = tid & 63;
  const int w    = tid >> 6;
  const int wr   = w >> 1, wc = w & 1;

  f32x4 acc[4][2];
#pragma unroll
  for (int m = 0; m < 4; m++)
#pragma unroll
    for (int n = 0; n < 2; n++) acc[m][n] = (f32x4){0.f, 0.f, 0.f, 0.f};

  const int srow = lane >> 2;        /* 0..15 row within a 16-row chunk */
  const int scol = (lane & 3) * 8;   /* 0,8,16,24 col (f32 elems) */

  /* staged f32 for one tile: A 2 chunks x 2 f32x4, B 1 chunk x 2 f32x4 = 24 VGPR */
  f32x4 fa[2][2], fb[2];

  auto loadst = [&](int k0) {
#pragma unroll
    for (int i = 0; i < 2; i++) {
      const float* pa = A + (size_t)(brow + (w + i * 4) * 16 + srow) * K + k0 + scol;
      fa[i][0] = *(const f32x4*)pa;
      fa[i][1] = *(const f32x4*)(pa + 4);
    }
    const float* pb = B + (size_t)(bcol + w * 16 + srow) * K + k0 + scol;
    fb[0] = *(const f32x4*)pb;
    fb[1] = *(const f32x4*)(pb + 4);
  };
  auto commit = [&](int buf) {
#pragma unroll
    for (int i = 0; i < 2; i++) {
      union { unsigned int u[4]; bf16x8 v8; } ua;
#pragma unroll
      for (int j = 0; j < 2; j++) {
        ua.u[2 * j]     = cvtpk_bf16(fa[i][j][0], fa[i][j][1]);
        ua.u[2 * j + 1] = cvtpk_bf16(fa[i][j][2], fa[i][j][3]);
      }
      *(bf16x8*)((char*)As + (size_t)buf * 8192 + (w + i * 4) * 1024 + lane * 16) = ua.v8;
    }
    union { unsigned int u[4]; bf16x8 v8; } ub;
#pragma unroll
    for (int j = 0; j < 2; j++) {
      ub.u[2 * j]     = cvtpk_bf16(fb[j][0], fb[j][1]);
      ub.u[2 * j + 1] = cvtpk_bf16(fb[j][2], fb[j][3]);
    }
    *(bf16x8*)((char*)Bs + (size_t)buf * 4096 + w * 1024 + lane * 16) = ub.v8;
  };

  loadst(0);
  commit(0);
  loadst(32);

  const int nk = K / 32;
  const int lrow_a = wr * 64 + (lane & 15);
  const int lrow_b = wc * 32 + (lane & 15);
  const int lcol   = (lane >> 4) * 8;

  for (int kt = 0; kt < nk; ++kt) {
    int buf = kt & 1;
    asm volatile("s_waitcnt lgkmcnt(0)" ::: "memory");  /* my ds ops for tile kt done */
    __builtin_amdgcn_s_barrier();
    __builtin_amdgcn_sched_barrier(0);
    if (kt + 1 < nk) commit(buf ^ 1);     /* regs from loadst(kt+1); compiler waits */
    if (kt + 2 < nk) loadst((kt + 2) * 32);
    bf16x8 a[4], b[2];
#pragma unroll
    for (int m = 0; m < 4; m++)
      a[m] = *(const bf16x8*)&As[(size_t)buf * 4096 + (lrow_a + m * 16) * 32 + lcol];
#pragma unroll
    for (int n = 0; n < 2; n++)
      b[n] = *(const bf16x8*)&Bs[(size_t)buf * 2048 + (lrow_b + n * 16) * 32 + lcol];
    __builtin_amdgcn_s_setprio(1);
#pragma unroll
    for (int m = 0; m < 4; m++)
#pragma unroll
      for (int n = 0; n < 2; n++)
        acc[m][n] = __builtin_amdgcn_mfma_f32_16x16x32_bf16(a[m], b[n], acc[m][n], 0, 0, 0);
    __builtin_amdgcn_s_setprio(0);
  }

  const int crow0 = brow + wr * 64;
  const int ccol0 = bcol + wc * 32;
  const int rsub  = (lane >> 4) * 4;
  const int csub  = lane & 15;
#pragma unroll
  for (int m = 0; m < 4; m++)
#pragma unroll
    for (int n = 0; n < 2; n++) {
      int col = ccol0 + n * 16 + csub;
      float bcol_v = BIAS_ROW ? 0.f : bias[col];
#pragma unroll
      for (int qq = 0; qq < 4; qq++) {
        int row = crow0 + m * 16 + rsub + qq;
        float bb = BIAS_ROW ? bias[row] : bcol_v;
        C[(size_t)row * N + col] = f2bf((acc[m][n][qq] + bb) * scale);
      }
    }
}

/* Q (prescaled by QSCALE), K, V^T projections straight from f32 inputs.
 * 1536 blocks of 128x64 tiles; panel-colocating XCD swizzle: 96 groups of 16
 * blocks; a group shares its A-panel (and, for z=2, a 1024-token v span) and
 * lands on one XCD via same-(mod 8) consecutive indices. */
__global__ __launch_bounds__(256, 4) void gemm_qkv(const float* __restrict__ q,
                                                   const float* __restrict__ k,
                                                   const float* __restrict__ v,
                                                   const float* __restrict__ Wq,
                                                   const float* __restrict__ Wk,
                                                   const float* __restrict__ Wv,
                                                   unsigned short* ws,
                                                   const float* __restrict__ bq,
                                                   const float* __restrict__ bk,
                                                   const float* __restrict__ bv) {
  __shared__ unsigned short As[2 * 128 * 32];   /* 16 KB */
  __shared__ unsigned short Bs[2 * 64 * 32];    /*  8 KB */
  const int i  = blockIdx.x;        /* 0..1535 */
  const int x  = i & 7;             /* target XCD (dispatch round-robin) */
  const int r  = i >> 3;            /* 0..191: slot within XCD */
  const int pm = r >> 4;            /* 0..11: panel-group within XCD */
  const int j  = r & 15;            /* 0..15: position within panel-group */
  const int p  = x * 12 + pm;       /* 0..95: global panel-group id */
  const int z  = p >> 5;            /* 0..2 */
  const int sub = p & 31;
  if (z < 2) {
    /* [MR][DM] = x_z @ W_z^T: A-panel = 128 input rows (shared by j=0..15) */
    gemm_f32_body<false>(As, Bs,
                         z ? k : q, z ? Wk : Wq, z ? bk : bq,
                         ws + OFF_QP + (size_t)z * SMK,
                         DM, DM, z ? 1.f : QSCALE, sub * 128, j * 64);
  } else {
    /* V^T [DM][MR] = Wv @ v^T: A-panel = 128 Wv rows, group spans 1024 v tokens */
    int apan = sub >> 2, vq = sub & 3;
    gemm_f32_body<true>(As, Bs,
                        Wv, v, bv,
                        ws + OFF_VP,
                        MR, DM, 1.f, apan * 128, (vq * 16 + j) * 64);
  }
}

/* ---------------- bf16 64x128 GEMM body (gemm_out only; R12-proven) ---------------- */
__device__ __forceinline__ void gemm_out_body(unsigned short* __restrict__ As,
                                              unsigned short* __restrict__ Bs,
                                              const unsigned short* __restrict__ A,
                                              const unsigned short* __restrict__ Bt,
                                              const float* __restrict__ bias,
                                              float* __restrict__ Cv,
                                              int N, int K,
                                              int brow, int bcol) {
  constexpr int BM = 64, BN = 128;
  const int tid  = threadIdx.x;
  const int lane = tid & 63;
  const int w    = tid >> 6;
  const int wr   = w >> 1, wc = w & 1;

  f32x4 acc[2][4];
#pragma unroll
  for (int m = 0; m < 2; m++)
#pragma unroll
    for (int n = 0; n < 4; n++) acc[m][n] = (f32x4){0.f, 0.f, 0.f, 0.f};

  const int srow = lane >> 2;
  const int scol = (lane & 3) * 8;

  auto stage = [&](int buf, int k0) {
#pragma unroll
    for (int c = w; c < BM / 16; c += 4)
      gload_lds16(A + (size_t)(brow + c * 16 + srow) * K + k0 + scol,
                  (char*)As + (size_t)buf * BM * 64 + c * 1024);
#pragma unroll
    for (int c = w; c < BN / 16; c += 4)
      gload_lds16(Bt + (size_t)(bcol + c * 16 + srow) * K + k0 + scol,
                  (char*)Bs + (size_t)buf * BN * 64 + c * 1024);
  };

  stage(0, 0);
  stage(1, 32);

  const int nk = K / 32;
  const int lrow_a = wr * (BM / 2) + (lane & 15);
  const int lrow_b = wc * (BN / 2) + (lane & 15);
  const int lcol   = (lane >> 4) * 8;

  int b0 = 0;
  for (int kt = 0; kt < nk; ++kt) {
    if (kt + 1 < nk) asm volatile("s_waitcnt vmcnt(3)" ::: "memory");
    else             asm volatile("s_waitcnt vmcnt(0)" ::: "memory");
    __builtin_amdgcn_s_barrier();
    __builtin_amdgcn_sched_barrier(0);
    if (kt + 2 < nk) {
      int bn = b0 + 2; if (bn >= 3) bn -= 3;
      stage(bn, (kt + 2) * 32);
    }
    bf16x8 a[2], b[4];
#pragma unroll
    for (int m = 0; m < 2; m++)
      a[m] = *(const bf16x8*)&As[(size_t)b0 * BM * 32 + (lrow_a + m * 16) * 32 + lcol];
#pragma unroll
    for (int n = 0; n < 4; n++)
      b[n] = *(const bf16x8*)&Bs[(size_t)b0 * BN * 32 + (lrow_b + n * 16) * 32 + lcol];
    __builtin_amdgcn_s_setprio(1);
#pragma unroll
    for (int m = 0; m < 2; m++)
#pragma unroll
      for (int n = 0; n < 4; n++)
        acc[m][n] = __builtin_amdgcn_mfma_f32_16x16x32_bf16(a[m], b[n], acc[m][n], 0, 0, 0);
    __builtin_amdgcn_s_setprio(0);
    b0 = (b0 == 2) ? 0 : b0 + 1;
  }

  const int crow0 = brow + wr * (BM / 2);
  const int ccol0 = bcol + wc * (BN / 2);
  const int rsub  = (lane >> 4) * 4;
  const int csub  = lane & 15;
#pragma unroll
  for (int m = 0; m < 2; m++)
#pragma unroll
    for (int n = 0; n < 4; n++) {
      int col = ccol0 + n * 16 + csub;
      float bv = bias[col];
#pragma unroll
      for (int qq = 0; qq < 4; qq++) {
        int row = crow0 + m * 16 + rsub + qq;
        Cv[(size_t)row * N + col] = acc[m][n][qq] + bv;
      }
    }
}

/* Output projection: 512 blocks, panel-colocating swizzle (64-row panels). */
__global__ __launch_bounds__(256) void gemm_out(const unsigned short* __restrict__ ws,
                                                const float* __restrict__ bo,
                                                float* __restrict__ out) {
  __shared__ unsigned short As[3 * 64 * 32];
  __shared__ unsigned short Bs[3 * 128 * 32];
  const int i  = blockIdx.x;        /* 0..511 */
  const int x  = i & 7;
  const int r  = i >> 3;            /* 0..63 */
  const int pm = r >> 3;            /* 0..7 */
  const int bx = r & 7;
  const int by = x * 8 + pm;        /* 0..63 */
  gemm_out_body(As, Bs,
                ws + OFF_CC, ws + OFF_WO, bo, out,
                DM, DM, by * 64, bx * 128);
}

/* ---------------- flash attention (R12 structure, measured 45.4us, UNCHANGED) -------
 * grid: 512 flat (XCD-swizzled). block: 512 = 8 waves in 2 split-K groups of 4.
 * Each group has its own double-buffered gload_lds K/V stream (4 x 16 KB).
 * Wave owns 32 q-rows (q = lane&31). S^T/O^T via 32x32x16 MFMA; P in registers via
 * cvt_pk + permlane32_swap; l accumulated in VALU f32. No-max softmax
 * (P = exp2(s), shift-invariant, bounded scores) -> split combine exact;
 * group B spills (O,l) to LDS scratch, group A adds and writes concat. */
__global__ __launch_bounds__(512, 4) void flash_attn(unsigned short* ws) {
  __shared__ __align__(16) unsigned char smem[65536];   /* 4 x (K 8KB | V 8KB) + f32 scratch */

  const int tid  = threadIdx.x;
  const int lane = tid & 63;
  const int w    = tid >> 6;        /* 0..7 */
  const int s    = w >> 2;          /* k-split group: 0 or 1 */
  const int wsub = w & 3;           /* wave within group -> q-subtile */
  const int q    = lane & 31;
  const int hi   = lane >> 5;
  const int swq  = q & 7;
  const int bid  = blockIdx.x;      /* 0..511 */
  const int swzb = (bid & 7) * 64 + (bid >> 3);   /* XCD-contiguous remap */
  const int qblk = swzb & 15;       /* 0..15, 128 q-rows each */
  const int bh   = swzb >> 4;       /* 0..31 */
  const int b    = bh >> 4, h = bh & 15;

  const unsigned short* Qp = ws + OFF_QP;
  const unsigned short* Kp = ws + OFF_KP;
  const unsigned short* Vp = ws + OFF_VP;
  unsigned short* CC = ws + OFF_CC;

  const unsigned short* Kg = Kp + (size_t)(b * SEQ) * DM + h * 64;          /* +row*DM */
  const unsigned short* Vg = Vp + (size_t)(h * 64) * MR + (size_t)b * SEQ;  /* +row*MR */

  /* Q B-fragments (col=q, k=hi*8+i within 16-d chunk c), prescaled by QSCALE */
  bf16x8 bqf[4];
  {
    const unsigned short* qrow =
        Qp + (size_t)(b * SEQ + qblk * 128 + wsub * 32 + q) * DM + h * 64;
#pragma unroll
    for (int c = 0; c < 4; c++)
      bqf[c] = *(const bf16x8*)(qrow + c * 16 + hi * 8);
  }

  f32x16 o_acc[2];
#pragma unroll
  for (int dt = 0; dt < 2; dt++)
#pragma unroll
    for (int r = 0; r < 16; r++) o_acc[dt][r] = 0.f;
  float l_run = 0.f;

  /* stage k-tile (s*16 + t) into this group's buffer `buf`; 4 waves of the group split it */
  auto stage = [&](int buf, int t) {
    const unsigned short* Kt = Kg + (size_t)(s * 16 + t) * 64 * DM;
    const unsigned short* Vt = Vg + (s * 16 + t) * 64;
    char* base = (char*)smem + (size_t)(s * 2 + buf) * 16384;
#pragma unroll
    for (int i = 0; i < 2; i++) {
      int slot = wsub * 128 + i * 64 + lane;   /* 16B slot 0..511 */
      int srow = slot >> 3;                    /* 0..63 */
      int gch  = (slot & 7) ^ (srow & 7);      /* inverse swizzle on global source */
      gload_lds16(Kt + (size_t)srow * DM + gch * 8, base + slot * 16);
      gload_lds16(Vt + (size_t)srow * MR + gch * 8, base + 8192 + slot * 16);
    }
  };

  stage(0, 0);

  for (int t = 0; t < 16; ++t) {
    int buf = t & 1;
    __syncthreads();   /* stage(t) drained (own-wave vmcnt) + all waves arrived */
    if (t + 1 < 16) stage(buf ^ 1, t + 1);
    const unsigned short* Kb = (const unsigned short*)(smem + (size_t)(s * 2 + buf) * 16384);
    const unsigned short* Vb = Kb + 4096;

    /* ---- S^T[64k][32q] = K · Q^T (log2-domain) ---- */
    f32x16 st0, st1;
#pragma unroll
    for (int r = 0; r < 16; r++) { st0[r] = 0.f; st1[r] = 0.f; }
    __builtin_amdgcn_s_setprio(1);
#pragma unroll
    for (int c = 0; c < 4; c++) {
      int ch = (((c << 1) | hi) ^ swq) << 3;
      bf16x8 ak0 = *(const bf16x8*)&Kb[q * 64 + ch];
      bf16x8 ak1 = *(const bf16x8*)&Kb[(32 + q) * 64 + ch];
      st0 = __builtin_amdgcn_mfma_f32_32x32x16_bf16(ak0, bqf[c], st0, 0, 0, 0);
      st1 = __builtin_amdgcn_mfma_f32_32x32x16_bf16(ak1, bqf[c], st1, 0, 0, 0);
    }
    __builtin_amdgcn_s_setprio(0);

    /* ---- P = exp2(S), packed to bf16 pairs; l accumulates in f32 ---- */
    unsigned int pk0[8], pk1[8];
    float lt = 0.f;
#pragma unroll
    for (int p = 0; p < 8; p++) {
      float a0 = __builtin_amdgcn_exp2f(st0[2 * p]);
      float a1 = __builtin_amdgcn_exp2f(st0[2 * p + 1]);
      float b0 = __builtin_amdgcn_exp2f(st1[2 * p]);
      float b1 = __builtin_amdgcn_exp2f(st1[2 * p + 1]);
      lt += (a0 + a1) + (b0 + b1);
      pk0[p] = cvtpk_bf16(a0, a1);
      pk1[p] = cvtpk_bf16(b0, b1);
    }
    l_run += lt;

    /* ---- redistribute hi-halves: pk[0..3] / pk[4..7] become PV B-frags ---- */
    plane32_swap(pk0[0], pk0[2]); plane32_swap(pk0[1], pk0[3]);
    plane32_swap(pk0[4], pk0[6]); plane32_swap(pk0[5], pk0[7]);
    plane32_swap(pk1[0], pk1[2]); plane32_swap(pk1[1], pk1[3]);
    plane32_swap(pk1[4], pk1[6]); plane32_swap(pk1[5], pk1[7]);

    /* ---- O^T[64d][32q] += V^T · P^T ---- */
    __builtin_amdgcn_s_setprio(1);
#pragma unroll
    for (int t4 = 0; t4 < 4; t4++) {              /* j-chunk of 16 */
      union { unsigned int u[4]; bf16x8 v; } pb;
      const unsigned int* src = (t4 < 2) ? pk0 : pk1;
      pb.u[0] = src[(t4 & 1) * 4 + 0];
      pb.u[1] = src[(t4 & 1) * 4 + 1];
      pb.u[2] = src[(t4 & 1) * 4 + 2];
      pb.u[3] = src[(t4 & 1) * 4 + 3];
      int ch = (((t4 << 1) | hi) ^ swq) << 3;
#pragma unroll
      for (int dt = 0; dt < 2; dt++) {
        bf16x8 av = *(const bf16x8*)&Vb[(dt * 32 + q) * 64 + ch];
        o_acc[dt] = __builtin_amdgcn_mfma_f32_32x32x16_bf16(av, pb.v, o_acc[dt], 0, 0, 0);
      }
    }
    __builtin_amdgcn_s_setprio(0);
  }

  /* ---- combine the two k-splits via LDS scratch (staging buffers are dead) ---- */
  __syncthreads();
  float* scr = (float*)smem;
  float lsum = l_run + __shfl_xor(l_run, 32, 64);   /* combine hi halves */
  if (s == 1) {
    int idx = (wsub * 64 + lane) * 33;              /* stride 33: conflict-free */
#pragma unroll
    for (int dt = 0; dt < 2; dt++)
#pragma unroll
      for (int r = 0; r < 16; r++) scr[idx + dt * 16 + r] = o_acc[dt][r];
    scr[idx + 32] = lsum;
  }
  __syncthreads();
  if (s == 0) {
    int idx = (wsub * 64 + lane) * 33;
#pragma unroll
    for (int dt = 0; dt < 2; dt++)
#pragma unroll
      for (int r = 0; r < 16; r++) o_acc[dt][r] += scr[idx + dt * 16 + r];
    float l = lsum + scr[idx + 32];
    float inv = 1.f / l;

    /* ---- epilogue: O^T[d][q], d = dt*32 + 8*(reg>>2) + 4*hi + (reg&3) ---- */
    int qg = b * SEQ + qblk * 128 + wsub * 32 + q;
    unsigned short* crow = CC + (size_t)qg * DM + h * 64;
#pragma unroll
    for (int dt = 0; dt < 2; dt++)
#pragma unroll
      for (int rq = 0; rq < 4; rq++) {
        ushort4 o;
        o.x = f2bf(o_acc[dt][4 * rq + 0] * inv);
        o.y = f2bf(o_acc[dt][4 * rq + 1] * inv);
        o.z = f2bf(o_acc[dt][4 * rq + 2] * inv);
        o.w = f2bf(o_acc[dt][4 * rq + 3] * inv);
        *(ushort4*)&crow[dt * 32 + rq * 8 + hi * 4] = o;
      }
  }
}

/* ---------------- launch ---------------- */
extern "C" void kernel_launch(void* const* d_in, const int* in_sizes, int n_in,
                              void* d_out, int out_size, void* d_ws, size_t ws_size,
                              hipStream_t stream) {
  const float* q  = (const float*)d_in[0];
  const float* k  = (const float*)d_in[1];
  const float* v  = (const float*)d_in[2];
  const float* Wq = (const float*)d_in[3];
  const float* bq = (const float*)d_in[4];
  const float* Wk = (const float*)d_in[5];
  const float* bk = (const float*)d_in[6];
  const float* Wv = (const float*)d_in[7];
  const float* bv = (const float*)d_in[8];
  const float* Wo = (const float*)d_in[9];
  const float* bo = (const float*)d_in[10];

  unsigned short* ws = (unsigned short*)d_ws;
  float* out = (float*)d_out;

  /* only Wo needs a bf16 copy */
  cvt_wo<<<dim3((W1M / 4) / 256), dim3(256), 0, stream>>>(Wo, ws + OFF_WO);

  /* Q (prescaled), K, V^T projections straight from f32: 1536 blocks of 128x64 */
  gemm_qkv<<<dim3(1536), dim3(256), 0, stream>>>(q, k, v, Wq, Wk, Wv, ws, bq, bk, bv);

  /* attention: 512 blocks x 512 threads, split-K x2 in-block (R9 structure) */
  flash_attn<<<dim3(512), dim3(512), 0, stream>>>(ws);

  /* output projection -> f32 d_out: flat 512 blocks, panel-colocating swizzle */
  gemm_out<<<dim3(512), dim3(256), 0, stream>>>(ws, bo, out);
}

// Round 16
// 130.067 us; speedup vs baseline: 1.0022x; 1.0022x over previous
//
#include <hip/hip_runtime.h>
#include <hip/hip_bf16.h>

typedef __attribute__((ext_vector_type(8))) short bf16x8;
typedef __attribute__((ext_vector_type(4))) float f32x4;
typedef __attribute__((ext_vector_type(16))) float f32x16;

#define DM   1024
#define SEQ  2048
#define NB   2
#define NH   16
#define MR   (NB*SEQ)            /* 4096 rows of the flattened [B*S, D] matrices */

#define SMK  (MR*DM)             /* 4194304 elements per [4096,1024] tensor */
#define W1M  (DM*DM)             /* 1048576 elements per weight matrix */

/* 0.125 * log2(e): folded into Q projection so attention uses exp2 directly */
#define QSCALE 0.18033688011112042f

/* workspace layout, in bf16 (ushort) units. concat aliases OFF_QB.
 * bf16 copies: Wq at 3*SMK, Wk at +W1M, Wo at OFF_WO, v at OFF_KB (=SMK). */
#define OFF_QB  ((size_t)0)
#define OFF_KB  ((size_t)SMK)                                   /* v_bf16 */
#define OFF_WQB ((size_t)(3*(size_t)SMK))                       /* Wq_bf, Wk_bf=+W1M */
#define OFF_WO  ((size_t)(3*(size_t)SMK + 3*(size_t)W1M))
#define OFF_QP  ((size_t)(3*(size_t)SMK + 4*(size_t)W1M))
#define OFF_KP  ((size_t)(4*(size_t)SMK + 4*(size_t)W1M))
#define OFF_VP  ((size_t)(5*(size_t)SMK + 4*(size_t)W1M))       /* V^T: [DM][MR] */
#define OFF_CC  ((size_t)0)

__device__ __forceinline__ unsigned short f2bf(float f) {
  union { __hip_bfloat16 b; unsigned short u; } cv;
  cv.b = __float2bfloat16(f);
  return cv.u;
}

/* v_cvt_pk_bf16_f32: packs (lo,hi) floats into one u32 of 2 bf16 */
__device__ __forceinline__ unsigned int cvtpk_bf16(float lo, float hi) {
  unsigned int r;
  asm("v_cvt_pk_bf16_f32 %0, %1, %2" : "=v"(r) : "v"(lo), "v"(hi));
  return r;
}

/* v_permlane32_swap_b32: a.upper32lanes <-> b.lower32lanes (both results used) */
__device__ __forceinline__ void plane32_swap(unsigned int& a, unsigned int& b) {
  asm("v_permlane32_swap_b32 %0, %1" : "+v"(a), "+v"(b));
}

/* ---------------- f32 -> bf16 for Wq, Wk, Wo, v (B-side + gemm_out operands) ------- */
__global__ __launch_bounds__(256) void cvt_all(const float* __restrict__ wq,
                                               const float* __restrict__ wk,
                                               const float* __restrict__ wo,
                                               const float* __restrict__ v,
                                               unsigned short* __restrict__ ws) {
  int i = blockIdx.x * 256 + threadIdx.x;
  const float* src;
  unsigned short* dst;
  int j;
  if (i < 3 * (W1M / 4)) {
    int z = i >> 18;                  /* W1M/4 = 2^18 */
    j = i & ((W1M / 4) - 1);
    src = (z == 0) ? wq : ((z == 1) ? wk : wo);
    dst = ws + ((z == 2) ? OFF_WO : OFF_WQB + (size_t)z * W1M);
  } else {
    j = i - 3 * (W1M / 4);
    src = v;
    dst = ws + OFF_KB;
  }
  float4 val = reinterpret_cast<const float4*>(src)[j];
  ushort4 o;
  o.x = f2bf(val.x); o.y = f2bf(val.y); o.z = f2bf(val.z); o.w = f2bf(val.w);
  reinterpret_cast<ushort4*>(dst)[j] = o;
}

/* ---------------- async global->LDS, 16B per lane ---------------- */
__device__ __forceinline__ void gload_lds16(const void* g, void* l) {
  __builtin_amdgcn_global_load_lds(
      (const __attribute__((address_space(1))) unsigned int*)g,
      (__attribute__((address_space(3))) unsigned int*)l,
      16, 0, 0);
}

/* ---------------- hybrid 128x128 GEMM: A f32 (gload_lds + in-reg cvt), B bf16 -------
 * A: [.][K] f32 rows at brow..+127 -> LDS as raw f32 (16KB/tile), source XOR-swizzled
 *    (16B granule ^ row&7) so fragment reads spread across banks; converted to bf16
 *    fragments in registers (2x ds_read_b128 + 4 cvt_pk each).
 * B: [.][K] bf16 rows at bcol..+127 (pre-converted) -> LDS linear (8KB/tile), as R12.
 * Both fire-and-forget: 3 buffers, depth-2 prefetch, s_barrier + vmcnt(6) counted
 * (6 gloads/thread/stage; never drains to 0 mid-loop). No reg-staging stall at all. */
template<bool BIAS_ROW>
__device__ __forceinline__ void gemm_hyb_body(unsigned char* __restrict__ Afs,
                                              unsigned short* __restrict__ Bs,
                                              const float* __restrict__ A,
                                              const unsigned short* __restrict__ B,
                                              const float* __restrict__ bias,
                                              unsigned short* __restrict__ C,
                                              int N, int K, float scale,
                                              int brow, int bcol) {
  const int tid  = threadIdx.x;
  const int lane = tid & 63;
  const int w    = tid >> 6;
  const int wr   = w >> 1, wc = w & 1;

  f32x4 acc[4][4];
#pragma unroll
  for (int m = 0; m < 4; m++)
#pragma unroll
    for (int n = 0; n < 4; n++) acc[m][n] = (f32x4){0.f, 0.f, 0.f, 0.f};

  /* A staging geometry: instruction j covers rows 8j..8j+7 (64 slots of 16B).
   * lane -> row 8j + (lane>>3), slot sl = lane&7; source granule gch = sl ^ (row&7). */
  const int arow_l = lane >> 3;            /* 0..7 */
  const int agch   = (lane & 7) ^ arow_l;  /* source 16B-granule (4 f32) */
  /* B staging (R12): row c*16 + (lane>>2), col (lane&3)*8 bf16, linear dest. */
  const int srow = lane >> 2;
  const int scol = (lane & 3) * 8;

  auto stage = [&](int buf, int k0) {
#pragma unroll
    for (int ii = 0; ii < 4; ii++) {       /* A: 4 gloads (16 row-chunks / 4 waves) */
      int j = w * 4 + ii;                  /* rows 8j.. */
      gload_lds16(A + (size_t)(brow + j * 8 + arow_l) * K + k0 + agch * 4,
                  Afs + (size_t)buf * 16384 + j * 1024);
    }
#pragma unroll
    for (int c = w; c < 8; c += 4)         /* B: 2 gloads */
      gload_lds16(B + (size_t)(bcol + c * 16 + srow) * K + k0 + scol,
                  (char*)Bs + (size_t)buf * 8192 + c * 1024);
  };

  stage(0, 0);
  stage(1, 32);

  const int nk = K / 32;
  const int g      = lane >> 4;                  /* 0..3 -> k-col block */
  const int lrow_a = wr * 64 + (lane & 15);
  const int lrow_b = wc * 64 + (lane & 15);
  const int lcol   = g * 8;
  const int s0 = (2 * g) ^ (lane & 7);           /* swizzled A slots (row&7 == lane&7) */
  const int s1 = (2 * g + 1) ^ (lane & 7);

  int b0 = 0;
  for (int kt = 0; kt < nk; ++kt) {
    if (kt + 1 < nk) asm volatile("s_waitcnt vmcnt(6)" ::: "memory");
    else             asm volatile("s_waitcnt vmcnt(0)" ::: "memory");
    __builtin_amdgcn_s_barrier();
    __builtin_amdgcn_sched_barrier(0);
    if (kt + 2 < nk) {
      int bn = b0 + 2; if (bn >= 3) bn -= 3;
      stage(bn, (kt + 2) * 32);
    }
    const unsigned char* Ab = Afs + (size_t)b0 * 16384;
    bf16x8 a[4], b[4];
#pragma unroll
    for (int m = 0; m < 4; m++) {
      int R = lrow_a + m * 16;
      f32x4 lo = *(const f32x4*)(Ab + R * 128 + s0 * 16);
      f32x4 hi = *(const f32x4*)(Ab + R * 128 + s1 * 16);
      union { unsigned int u[4]; bf16x8 v8; } ua;
      ua.u[0] = cvtpk_bf16(lo[0], lo[1]);
      ua.u[1] = cvtpk_bf16(lo[2], lo[3]);
      ua.u[2] = cvtpk_bf16(hi[0], hi[1]);
      ua.u[3] = cvtpk_bf16(hi[2], hi[3]);
      a[m] = ua.v8;
    }
#pragma unroll
    for (int n = 0; n < 4; n++)
      b[n] = *(const bf16x8*)&Bs[(size_t)b0 * 4096 + (lrow_b + n * 16) * 32 + lcol];
    __builtin_amdgcn_s_setprio(1);
#pragma unroll
    for (int m = 0; m < 4; m++)
#pragma unroll
      for (int n = 0; n < 4; n++)
        acc[m][n] = __builtin_amdgcn_mfma_f32_16x16x32_bf16(a[m], b[n], acc[m][n], 0, 0, 0);
    __builtin_amdgcn_s_setprio(0);
    b0 = (b0 == 2) ? 0 : b0 + 1;
  }

  const int crow0 = brow + wr * 64;
  const int ccol0 = bcol + wc * 64;
  const int rsub  = (lane >> 4) * 4;
  const int csub  = lane & 15;
#pragma unroll
  for (int m = 0; m < 4; m++)
#pragma unroll
    for (int n = 0; n < 4; n++) {
      int col = ccol0 + n * 16 + csub;
      float bcol_v = BIAS_ROW ? 0.f : bias[col];
#pragma unroll
      for (int qq = 0; qq < 4; qq++) {
        int row = crow0 + m * 16 + rsub + qq;
        float bb = BIAS_ROW ? bias[row] : bcol_v;
        C[(size_t)row * N + col] = f2bf((acc[m][n][qq] + bb) * scale);
      }
    }
}

/* Q (prescaled), K, V^T projections. A-side f32 direct (q, k, Wv); B-side bf16
 * pre-converted (Wq, Wk, v). Flat 768 blocks, panel-colocating XCD swizzle (R10). */
__global__ __launch_bounds__(256, 2) void gemm_qkv(const float* __restrict__ q,
                                                   const float* __restrict__ k,
                                                   const float* __restrict__ Wv,
                                                   unsigned short* ws,
                                                   const float* __restrict__ bq,
                                                   const float* __restrict__ bk,
                                                   const float* __restrict__ bv) {
  __shared__ __align__(16) unsigned char Afs[3 * 16384];   /* 48 KB f32 A tiles */
  __shared__ unsigned short Bs[3 * 4096];                  /* 24 KB bf16 B tiles */
  const int i  = blockIdx.x;        /* 0..767 */
  const int x  = i & 7;             /* target XCD (dispatch round-robin) */
  const int r  = i >> 3;            /* 0..95: slot within XCD */
  const int pm = r >> 3;            /* 0..11 */
  const int bx = r & 7;             /* 0..7: position within panel-group */
  const int p  = x * 12 + pm;       /* 0..95: panel-group id */
  const int z  = p >> 5;            /* 0..2 */
  const int by = p & 31;            /* 0..31: panel index */
  if (z < 2) {
    gemm_hyb_body<false>(Afs, Bs,
                         z ? k : q, ws + OFF_WQB + (size_t)z * W1M, z ? bk : bq,
                         ws + OFF_QP + (size_t)z * SMK,
                         DM, DM, z ? 1.f : QSCALE, by * 128, bx * 128);
  } else {
    /* V^T [DM][MR] = Wv @ v^T: A = Wv f32 rows (bx), B = v_bf rows (by), bias/row */
    gemm_hyb_body<true>(Afs, Bs,
                        Wv, ws + OFF_KB, bv,
                        ws + OFF_VP,
                        MR, DM, 1.f, bx * 128, by * 128);
  }
}

/* ---------------- bf16 64x128 GEMM body (gemm_out only; R12-proven) ---------------- */
__device__ __forceinline__ void gemm_out_body(unsigned short* __restrict__ As,
                                              unsigned short* __restrict__ Bs,
                                              const unsigned short* __restrict__ A,
                                              const unsigned short* __restrict__ Bt,
                                              const float* __restrict__ bias,
                                              float* __restrict__ Cv,
                                              int N, int K,
                                              int brow, int bcol) {
  constexpr int BM = 64, BN = 128;
  const int tid  = threadIdx.x;
  const int lane = tid & 63;
  const int w    = tid >> 6;
  const int wr   = w >> 1, wc = w & 1;

  f32x4 acc[2][4];
#pragma unroll
  for (int m = 0; m < 2; m++)
#pragma unroll
    for (int n = 0; n < 4; n++) acc[m][n] = (f32x4){0.f, 0.f, 0.f, 0.f};

  const int srow = lane >> 2;
  const int scol = (lane & 3) * 8;

  auto stage = [&](int buf, int k0) {
#pragma unroll
    for (int c = w; c < BM / 16; c += 4)
      gload_lds16(A + (size_t)(brow + c * 16 + srow) * K + k0 + scol,
                  (char*)As + (size_t)buf * BM * 64 + c * 1024);
#pragma unroll
    for (int c = w; c < BN / 16; c += 4)
      gload_lds16(Bt + (size_t)(bcol + c * 16 + srow) * K + k0 + scol,
                  (char*)Bs + (size_t)buf * BN * 64 + c * 1024);
  };

  stage(0, 0);
  stage(1, 32);

  const int nk = K / 32;
  const int lrow_a = wr * (BM / 2) + (lane & 15);
  const int lrow_b = wc * (BN / 2) + (lane & 15);
  const int lcol   = (lane >> 4) * 8;

  int b0 = 0;
  for (int kt = 0; kt < nk; ++kt) {
    if (kt + 1 < nk) asm volatile("s_waitcnt vmcnt(3)" ::: "memory");
    else             asm volatile("s_waitcnt vmcnt(0)" ::: "memory");
    __builtin_amdgcn_s_barrier();
    __builtin_amdgcn_sched_barrier(0);
    if (kt + 2 < nk) {
      int bn = b0 + 2; if (bn >= 3) bn -= 3;
      stage(bn, (kt + 2) * 32);
    }
    bf16x8 a[2], b[4];
#pragma unroll
    for (int m = 0; m < 2; m++)
      a[m] = *(const bf16x8*)&As[(size_t)b0 * BM * 32 + (lrow_a + m * 16) * 32 + lcol];
#pragma unroll
    for (int n = 0; n < 4; n++)
      b[n] = *(const bf16x8*)&Bs[(size_t)b0 * BN * 32 + (lrow_b + n * 16) * 32 + lcol];
    __builtin_amdgcn_s_setprio(1);
#pragma unroll
    for (int m = 0; m < 2; m++)
#pragma unroll
      for (int n = 0; n < 4; n++)
        acc[m][n] = __builtin_amdgcn_mfma_f32_16x16x32_bf16(a[m], b[n], acc[m][n], 0, 0, 0);
    __builtin_amdgcn_s_setprio(0);
    b0 = (b0 == 2) ? 0 : b0 + 1;
  }

  const int crow0 = brow + wr * (BM / 2);
  const int ccol0 = bcol + wc * (BN / 2);
  const int rsub  = (lane >> 4) * 4;
  const int csub  = lane & 15;
#pragma unroll
  for (int m = 0; m < 2; m++)
#pragma unroll
    for (int n = 0; n < 4; n++) {
      int col = ccol0 + n * 16 + csub;
      float bv = bias[col];
#pragma unroll
      for (int qq = 0; qq < 4; qq++) {
        int row = crow0 + m * 16 + rsub + qq;
        Cv[(size_t)row * N + col] = acc[m][n][qq] + bv;
      }
    }
}

/* Output projection: 512 blocks, panel-colocating swizzle (64-row panels). */
__global__ __launch_bounds__(256) void gemm_out(const unsigned short* __restrict__ ws,
                                                const float* __restrict__ bo,
                                                float* __restrict__ out) {
  __shared__ unsigned short As[3 * 64 * 32];
  __shared__ unsigned short Bs[3 * 128 * 32];
  const int i  = blockIdx.x;        /* 0..511 */
  const int x  = i & 7;
  const int r  = i >> 3;            /* 0..63 */
  const int pm = r >> 3;            /* 0..7 */
  const int bx = r & 7;
  const int by = x * 8 + pm;        /* 0..63 */
  gemm_out_body(As, Bs,
                ws + OFF_CC, ws + OFF_WO, bo, out,
                DM, DM, by * 64, bx * 128);
}

/* ---------------- flash attention (R12 structure, measured 45.4us, UNCHANGED) -------
 * grid: 512 flat (XCD-swizzled). block: 512 = 8 waves in 2 split-K groups of 4.
 * Each group has its own double-buffered gload_lds K/V stream (4 x 16 KB).
 * Wave owns 32 q-rows (q = lane&31). S^T/O^T via 32x32x16 MFMA; P in registers via
 * cvt_pk + permlane32_swap; l accumulated in VALU f32. No-max softmax
 * (P = exp2(s), shift-invariant, bounded scores) -> split combine exact;
 * group B spills (O,l) to LDS scratch, group A adds and writes concat. */
__global__ __launch_bounds__(512, 4) void flash_attn(unsigned short* ws) {
  __shared__ __align__(16) unsigned char smem[65536];   /* 4 x (K 8KB | V 8KB) + f32 scratch */

  const int tid  = threadIdx.x;
  const int lane = tid & 63;
  const int w    = tid >> 6;        /* 0..7 */
  const int s    = w >> 2;          /* k-split group: 0 or 1 */
  const int wsub = w & 3;           /* wave within group -> q-subtile */
  const int q    = lane & 31;
  const int hi   = lane >> 5;
  const int swq  = q & 7;
  const int bid  = blockIdx.x;      /* 0..511 */
  const int swzb = (bid & 7) * 64 + (bid >> 3);   /* XCD-contiguous remap */
  const int qblk = swzb & 15;       /* 0..15, 128 q-rows each */
  const int bh   = swzb >> 4;       /* 0..31 */
  const int b    = bh >> 4, h = bh & 15;

  const unsigned short* Qp = ws + OFF_QP;
  const unsigned short* Kp = ws + OFF_KP;
  const unsigned short* Vp = ws + OFF_VP;
  unsigned short* CC = ws + OFF_CC;

  const unsigned short* Kg = Kp + (size_t)(b * SEQ) * DM + h * 64;          /* +row*DM */
  const unsigned short* Vg = Vp + (size_t)(h * 64) * MR + (size_t)b * SEQ;  /* +row*MR */

  /* Q B-fragments (col=q, k=hi*8+i within 16-d chunk c), prescaled by QSCALE */
  bf16x8 bqf[4];
  {
    const unsigned short* qrow =
        Qp + (size_t)(b * SEQ + qblk * 128 + wsub * 32 + q) * DM + h * 64;
#pragma unroll
    for (int c = 0; c < 4; c++)
      bqf[c] = *(const bf16x8*)(qrow + c * 16 + hi * 8);
  }

  f32x16 o_acc[2];
#pragma unroll
  for (int dt = 0; dt < 2; dt++)
#pragma unroll
    for (int r = 0; r < 16; r++) o_acc[dt][r] = 0.f;
  float l_run = 0.f;

  /* stage k-tile (s*16 + t) into this group's buffer `buf`; 4 waves of the group split it */
  auto stage = [&](int buf, int t) {
    const unsigned short* Kt = Kg + (size_t)(s * 16 + t) * 64 * DM;
    const unsigned short* Vt = Vg + (s * 16 + t) * 64;
    char* base = (char*)smem + (size_t)(s * 2 + buf) * 16384;
#pragma unroll
    for (int i = 0; i < 2; i++) {
      int slot = wsub * 128 + i * 64 + lane;   /* 16B slot 0..511 */
      int srow = slot >> 3;                    /* 0..63 */
      int gch  = (slot & 7) ^ (srow & 7);      /* inverse swizzle on global source */
      gload_lds16(Kt + (size_t)srow * DM + gch * 8, base + slot * 16);
      gload_lds16(Vt + (size_t)srow * MR + gch * 8, base + 8192 + slot * 16);
    }
  };

  stage(0, 0);

  for (int t = 0; t < 16; ++t) {
    int buf = t & 1;
    __syncthreads();   /* stage(t) drained (own-wave vmcnt) + all waves arrived */
    if (t + 1 < 16) stage(buf ^ 1, t + 1);
    const unsigned short* Kb = (const unsigned short*)(smem + (size_t)(s * 2 + buf) * 16384);
    const unsigned short* Vb = Kb + 4096;

    /* ---- S^T[64k][32q] = K · Q^T (log2-domain) ---- */
    f32x16 st0, st1;
#pragma unroll
    for (int r = 0; r < 16; r++) { st0[r] = 0.f; st1[r] = 0.f; }
    __builtin_amdgcn_s_setprio(1);
#pragma unroll
    for (int c = 0; c < 4; c++) {
      int ch = (((c << 1) | hi) ^ swq) << 3;
      bf16x8 ak0 = *(const bf16x8*)&Kb[q * 64 + ch];
      bf16x8 ak1 = *(const bf16x8*)&Kb[(32 + q) * 64 + ch];
      st0 = __builtin_amdgcn_mfma_f32_32x32x16_bf16(ak0, bqf[c], st0, 0, 0, 0);
      st1 = __builtin_amdgcn_mfma_f32_32x32x16_bf16(ak1, bqf[c], st1, 0, 0, 0);
    }
    __builtin_amdgcn_s_setprio(0);

    /* ---- P = exp2(S), packed to bf16 pairs; l accumulates in f32 ---- */
    unsigned int pk0[8], pk1[8];
    float lt = 0.f;
#pragma unroll
    for (int p = 0; p < 8; p++) {
      float a0 = __builtin_amdgcn_exp2f(st0[2 * p]);
      float a1 = __builtin_amdgcn_exp2f(st0[2 * p + 1]);
      float b0 = __builtin_amdgcn_exp2f(st1[2 * p]);
      float b1 = __builtin_amdgcn_exp2f(st1[2 * p + 1]);
      lt += (a0 + a1) + (b0 + b1);
      pk0[p] = cvtpk_bf16(a0, a1);
      pk1[p] = cvtpk_bf16(b0, b1);
    }
    l_run += lt;

    /* ---- redistribute hi-halves: pk[0..3] / pk[4..7] become PV B-frags ---- */
    plane32_swap(pk0[0], pk0[2]); plane32_swap(pk0[1], pk0[3]);
    plane32_swap(pk0[4], pk0[6]); plane32_swap(pk0[5], pk0[7]);
    plane32_swap(pk1[0], pk1[2]); plane32_swap(pk1[1], pk1[3]);
    plane32_swap(pk1[4], pk1[6]); plane32_swap(pk1[5], pk1[7]);

    /* ---- O^T[64d][32q] += V^T · P^T ---- */
    __builtin_amdgcn_s_setprio(1);
#pragma unroll
    for (int t4 = 0; t4 < 4; t4++) {              /* j-chunk of 16 */
      union { unsigned int u[4]; bf16x8 v; } pb;
      const unsigned int* src = (t4 < 2) ? pk0 : pk1;
      pb.u[0] = src[(t4 & 1) * 4 + 0];
      pb.u[1] = src[(t4 & 1) * 4 + 1];
      pb.u[2] = src[(t4 & 1) * 4 + 2];
      pb.u[3] = src[(t4 & 1) * 4 + 3];
      int ch = (((t4 << 1) | hi) ^ swq) << 3;
#pragma unroll
      for (int dt = 0; dt < 2; dt++) {
        bf16x8 av = *(const bf16x8*)&Vb[(dt * 32 + q) * 64 + ch];
        o_acc[dt] = __builtin_amdgcn_mfma_f32_32x32x16_bf16(av, pb.v, o_acc[dt], 0, 0, 0);
      }
    }
    __builtin_amdgcn_s_setprio(0);
  }

  /* ---- combine the two k-splits via LDS scratch (staging buffers are dead) ---- */
  __syncthreads();
  float* scr = (float*)smem;
  float lsum = l_run + __shfl_xor(l_run, 32, 64);   /* combine hi halves */
  if (s == 1) {
    int idx = (wsub * 64 + lane) * 33;              /* stride 33: conflict-free */
#pragma unroll
    for (int dt = 0; dt < 2; dt++)
#pragma unroll
      for (int r = 0; r < 16; r++) scr[idx + dt * 16 + r] = o_acc[dt][r];
    scr[idx + 32] = lsum;
  }
  __syncthreads();
  if (s == 0) {
    int idx = (wsub * 64 + lane) * 33;
#pragma unroll
    for (int dt = 0; dt < 2; dt++)
#pragma unroll
      for (int r = 0; r < 16; r++) o_acc[dt][r] += scr[idx + dt * 16 + r];
    float l = lsum + scr[idx + 32];
    float inv = 1.f / l;

    /* ---- epilogue: O^T[d][q], d = dt*32 + 8*(reg>>2) + 4*hi + (reg&3) ---- */
    int qg = b * SEQ + qblk * 128 + wsub * 32 + q;
    unsigned short* crow = CC + (size_t)qg * DM + h * 64;
#pragma unroll
    for (int dt = 0; dt < 2; dt++)
#pragma unroll
      for (int rq = 0; rq < 4; rq++) {
        ushort4 o;
        o.x = f2bf(o_acc[dt][4 * rq + 0] * inv);
        o.y = f2bf(o_acc[dt][4 * rq + 1] * inv);
        o.z = f2bf(o_acc[dt][4 * rq + 2] * inv);
        o.w = f2bf(o_acc[dt][4 * rq + 3] * inv);
        *(ushort4*)&crow[dt * 32 + rq * 8 + hi * 4] = o;
      }
  }
}

/* ---------------- launch ---------------- */
extern "C" void kernel_launch(void* const* d_in, const int* in_sizes, int n_in,
                              void* d_out, int out_size, void* d_ws, size_t ws_size,
                              hipStream_t stream) {
  const float* q  = (const float*)d_in[0];
  const float* k  = (const float*)d_in[1];
  const float* v  = (const float*)d_in[2];
  const float* Wq = (const float*)d_in[3];
  const float* bq = (const float*)d_in[4];
  const float* Wk = (const float*)d_in[5];
  const float* bk = (const float*)d_in[6];
  const float* Wv = (const float*)d_in[7];
  const float* bv = (const float*)d_in[8];
  const float* Wo = (const float*)d_in[9];
  const float* bo = (const float*)d_in[10];

  unsigned short* ws = (unsigned short*)d_ws;
  float* out = (float*)d_out;

  /* bf16 copies of Wq, Wk, Wo, v (B-side + gemm_out operands): ~7us, BW-bound */
  cvt_all<<<dim3((3 * (W1M / 4) + SMK / 4) / 256), dim3(256), 0, stream>>>(
      Wq, Wk, Wo, v, ws);

  /* Q (prescaled), K, V^T projections: hybrid A-f32/B-bf16, 768 blocks */
  gemm_qkv<<<dim3(768), dim3(256), 0, stream>>>(q, k, Wv, ws, bq, bk, bv);

  /* attention: 512 blocks x 512 threads, split-K x2 in-block (R9 structure) */
  flash_attn<<<dim3(512), dim3(512), 0, stream>>>(ws);

  /* output projection -> f32 d_out: flat 512 blocks, panel-colocating swizzle */
  gemm_out<<<dim3(512), dim3(256), 0, stream>>>(ws, bo, out);
}

// Round 17
// 109.712 us; speedup vs baseline: 1.1881x; 1.1855x over previous
//
#include <hip/hip_runtime.h>
#include <hip/hip_bf16.h>

typedef __attribute__((ext_vector_type(8))) short bf16x8;
typedef __attribute__((ext_vector_type(4))) float f32x4;
typedef __attribute__((ext_vector_type(16))) float f32x16;

#define DM   1024
#define SEQ  2048
#define NB   2
#define NH   16
#define MR   (NB*SEQ)            /* 4096 rows of the flattened [B*S, D] matrices */

#define SMK  (MR*DM)             /* 4194304 elements per [4096,1024] tensor */
#define W1M  (DM*DM)             /* 1048576 elements per weight matrix */

/* 0.125 * log2(e): folded into Q projection so attention uses exp2 directly */
#define QSCALE 0.18033688011112042f

/* workspace layout, in bf16 (ushort) units. concat aliases OFF_QB.
 * bf16 copies: Wq at 3*SMK, Wk at +W1M, Wo at OFF_WO, v at OFF_KB (=SMK). */
#define OFF_QB  ((size_t)0)
#define OFF_KB  ((size_t)SMK)                                   /* v_bf16 */
#define OFF_WQB ((size_t)(3*(size_t)SMK))                       /* Wq_bf, Wk_bf=+W1M */
#define OFF_WO  ((size_t)(3*(size_t)SMK + 3*(size_t)W1M))
#define OFF_QP  ((size_t)(3*(size_t)SMK + 4*(size_t)W1M))
#define OFF_KP  ((size_t)(4*(size_t)SMK + 4*(size_t)W1M))
#define OFF_VP  ((size_t)(5*(size_t)SMK + 4*(size_t)W1M))       /* V^T: [DM][MR] */
#define OFF_CC  ((size_t)0)

__device__ __forceinline__ unsigned short f2bf(float f) {
  union { __hip_bfloat16 b; unsigned short u; } cv;
  cv.b = __float2bfloat16(f);
  return cv.u;
}

/* v_cvt_pk_bf16_f32: packs (lo,hi) floats into one u32 of 2 bf16 */
__device__ __forceinline__ unsigned int cvtpk_bf16(float lo, float hi) {
  unsigned int r;
  asm("v_cvt_pk_bf16_f32 %0, %1, %2" : "=v"(r) : "v"(lo), "v"(hi));
  return r;
}

/* v_permlane32_swap_b32: a.upper32lanes <-> b.lower32lanes (both results used) */
__device__ __forceinline__ void plane32_swap(unsigned int& a, unsigned int& b) {
  asm("v_permlane32_swap_b32 %0, %1" : "+v"(a), "+v"(b));
}

/* ---------------- f32 -> bf16 for Wq, Wk, Wo, v (B-side + gemm_out operands) ------- */
__global__ __launch_bounds__(256) void cvt_all(const float* __restrict__ wq,
                                               const float* __restrict__ wk,
                                               const float* __restrict__ wo,
                                               const float* __restrict__ v,
                                               unsigned short* __restrict__ ws) {
  int i = blockIdx.x * 256 + threadIdx.x;
  const float* src;
  unsigned short* dst;
  int j;
  if (i < 3 * (W1M / 4)) {
    int z = i >> 18;                  /* W1M/4 = 2^18 */
    j = i & ((W1M / 4) - 1);
    src = (z == 0) ? wq : ((z == 1) ? wk : wo);
    dst = ws + ((z == 2) ? OFF_WO : OFF_WQB + (size_t)z * W1M);
  } else {
    j = i - 3 * (W1M / 4);
    src = v;
    dst = ws + OFF_KB;
  }
  float4 val = reinterpret_cast<const float4*>(src)[j];
  ushort4 o;
  o.x = f2bf(val.x); o.y = f2bf(val.y); o.z = f2bf(val.z); o.w = f2bf(val.w);
  reinterpret_cast<ushort4*>(dst)[j] = o;
}

/* ---------------- async global->LDS, 16B per lane ---------------- */
__device__ __forceinline__ void gload_lds16(const void* g, void* l) {
  __builtin_amdgcn_global_load_lds(
      (const __attribute__((address_space(1))) unsigned int*)g,
      (__attribute__((address_space(3))) unsigned int*)l,
      16, 0, 0);
}

/* ---------------- hybrid 128x128 GEMM v2: A f32 reg-staged (2 regsets, 2-iter
 * flight), B bf16 via fire-and-forget gload_lds. LDS = 2 x (8KB A + 8KB B) = 32KB.
 * Per iter: vmcnt(4) covers B (staged 1 iter ago) and implies older A-loads done
 * (FIFO) so commitA never waits; commit tile kt+1 (regs loaded at kt-1), stage B
 * tile kt+1, load A tile kt+3 into the freed regset. Loop unrolled x2 so regset
 * indexing is compile-time. */
template<bool BIAS_ROW>
__device__ __forceinline__ void gemm_hyb2_body(unsigned short* __restrict__ As,
                                               unsigned short* __restrict__ Bs,
                                               const float* __restrict__ A,
                                               const unsigned short* __restrict__ B,
                                               const float* __restrict__ bias,
                                               unsigned short* __restrict__ C,
                                               int N, int K, float scale,
                                               int brow, int bcol) {
  const int tid  = threadIdx.x;
  const int lane = tid & 63;
  const int w    = tid >> 6;
  const int wr   = w >> 1, wc = w & 1;

  f32x4 acc[4][4];
#pragma unroll
  for (int m = 0; m < 4; m++)
#pragma unroll
    for (int n = 0; n < 4; n++) acc[m][n] = (f32x4){0.f, 0.f, 0.f, 0.f};

  const int srow = lane >> 2;        /* 0..15 row within a 16-row chunk */
  const int scol = (lane & 3) * 8;   /* 0,8,16,24 col */

  /* two named A staging register sets (16 VGPR each) */
  f32x4 ra0[2][2], ra1[2][2];

  auto loadA = [&](int k0, f32x4 (&fa)[2][2]) {
#pragma unroll
    for (int i = 0; i < 2; i++) {
      const float* pa = A + (size_t)(brow + (w + i * 4) * 16 + srow) * K + k0 + scol;
      fa[i][0] = *(const f32x4*)pa;
      fa[i][1] = *(const f32x4*)(pa + 4);
    }
  };
  auto commitA = [&](int buf, f32x4 (&fa)[2][2]) {
#pragma unroll
    for (int i = 0; i < 2; i++) {
      union { unsigned int u[4]; bf16x8 v8; } ua;
#pragma unroll
      for (int j = 0; j < 2; j++) {
        ua.u[2 * j]     = cvtpk_bf16(fa[i][j][0], fa[i][j][1]);
        ua.u[2 * j + 1] = cvtpk_bf16(fa[i][j][2], fa[i][j][3]);
      }
      *(bf16x8*)((char*)As + (size_t)buf * 8192 + (w + i * 4) * 1024 + lane * 16) = ua.v8;
    }
  };
  auto stageB = [&](int buf, int k0) {
#pragma unroll
    for (int c = w; c < 8; c += 4)
      gload_lds16(B + (size_t)(bcol + c * 16 + srow) * K + k0 + scol,
                  (char*)Bs + (size_t)buf * 8192 + c * 1024);
  };

  const int nk = K / 32;             /* 32, even */

  /* prologue: tile0 committed; tiles 1,2 A-loads + tile0 B in flight */
  loadA(0, ra0);
  commitA(0, ra0);
  loadA(32, ra1);
  stageB(0, 0);
  loadA(64, ra0);

  const int lrow_a = wr * 64 + (lane & 15);
  const int lrow_b = wc * 64 + (lane & 15);
  const int lcol   = (lane >> 4) * 8;

  auto iter = [&](int kt, f32x4 (&rs)[2][2]) {
    if (kt + 2 < nk) asm volatile("s_waitcnt vmcnt(4) lgkmcnt(0)" ::: "memory");
    else             asm volatile("s_waitcnt vmcnt(0) lgkmcnt(0)" ::: "memory");
    __builtin_amdgcn_s_barrier();
    __builtin_amdgcn_sched_barrier(0);
    int buf = kt & 1;
    bf16x8 a[4], b[4];
#pragma unroll
    for (int m = 0; m < 4; m++)
      a[m] = *(const bf16x8*)&As[(size_t)buf * 4096 + (lrow_a + m * 16) * 32 + lcol];
#pragma unroll
    for (int n = 0; n < 4; n++)
      b[n] = *(const bf16x8*)&Bs[(size_t)buf * 4096 + (lrow_b + n * 16) * 32 + lcol];
    if (kt + 1 < nk) {
      commitA(buf ^ 1, rs);               /* tile kt+1: regs loaded at kt-1 (done) */
      stageB(buf ^ 1, (kt + 1) * 32);     /* tile kt+1 B: fire-and-forget */
    }
    if (kt + 3 < nk) loadA((kt + 3) * 32, rs);   /* regset just freed */
    __builtin_amdgcn_s_setprio(1);
#pragma unroll
    for (int m = 0; m < 4; m++)
#pragma unroll
      for (int n = 0; n < 4; n++)
        acc[m][n] = __builtin_amdgcn_mfma_f32_16x16x32_bf16(a[m], b[n], acc[m][n], 0, 0, 0);
    __builtin_amdgcn_s_setprio(0);
  };

  for (int kt = 0; kt < nk; kt += 2) {
    iter(kt,     ra1);     /* commits tile kt+1 (odd)  -> regset 1 */
    iter(kt + 1, ra0);     /* commits tile kt+2 (even) -> regset 0 */
  }

  const int crow0 = brow + wr * 64;
  const int ccol0 = bcol + wc * 64;
  const int rsub  = (lane >> 4) * 4;
  const int csub  = lane & 15;
#pragma unroll
  for (int m = 0; m < 4; m++)
#pragma unroll
    for (int n = 0; n < 4; n++) {
      int col = ccol0 + n * 16 + csub;
      float bcol_v = BIAS_ROW ? 0.f : bias[col];
#pragma unroll
      for (int qq = 0; qq < 4; qq++) {
        int row = crow0 + m * 16 + rsub + qq;
        float bb = BIAS_ROW ? bias[row] : bcol_v;
        C[(size_t)row * N + col] = f2bf((acc[m][n][qq] + bb) * scale);
      }
    }
}

/* Q (prescaled), K, V^T projections. A-side f32 direct (q, k, Wv); B-side bf16
 * pre-converted (Wq, Wk, v). Flat 768 blocks, panel-colocating XCD swizzle (R10). */
__global__ __launch_bounds__(256, 3) void gemm_qkv(const float* __restrict__ q,
                                                   const float* __restrict__ k,
                                                   const float* __restrict__ Wv,
                                                   unsigned short* ws,
                                                   const float* __restrict__ bq,
                                                   const float* __restrict__ bk,
                                                   const float* __restrict__ bv) {
  __shared__ unsigned short As[2 * 128 * 32];   /* 16 KB */
  __shared__ unsigned short Bs[2 * 128 * 32];   /* 16 KB */
  const int i  = blockIdx.x;        /* 0..767 */
  const int x  = i & 7;             /* target XCD (dispatch round-robin) */
  const int r  = i >> 3;            /* 0..95: slot within XCD */
  const int pm = r >> 3;            /* 0..11 */
  const int bx = r & 7;             /* 0..7: position within panel-group */
  const int p  = x * 12 + pm;       /* 0..95: panel-group id */
  const int z  = p >> 5;            /* 0..2 */
  const int by = p & 31;            /* 0..31: panel index */
  if (z < 2) {
    gemm_hyb2_body<false>(As, Bs,
                          z ? k : q, ws + OFF_WQB + (size_t)z * W1M, z ? bk : bq,
                          ws + OFF_QP + (size_t)z * SMK,
                          DM, DM, z ? 1.f : QSCALE, by * 128, bx * 128);
  } else {
    /* V^T [DM][MR] = Wv @ v^T: A = Wv f32 rows (bx), B = v_bf rows (by), bias/row */
    gemm_hyb2_body<true>(As, Bs,
                         Wv, ws + OFF_KB, bv,
                         ws + OFF_VP,
                         MR, DM, 1.f, bx * 128, by * 128);
  }
}

/* ---------------- bf16 64x128 GEMM body (gemm_out only; R12-proven) ---------------- */
__device__ __forceinline__ void gemm_out_body(unsigned short* __restrict__ As,
                                              unsigned short* __restrict__ Bs,
                                              const unsigned short* __restrict__ A,
                                              const unsigned short* __restrict__ Bt,
                                              const float* __restrict__ bias,
                                              float* __restrict__ Cv,
                                              int N, int K,
                                              int brow, int bcol) {
  constexpr int BM = 64, BN = 128;
  const int tid  = threadIdx.x;
  const int lane = tid & 63;
  const int w    = tid >> 6;
  const int wr   = w >> 1, wc = w & 1;

  f32x4 acc[2][4];
#pragma unroll
  for (int m = 0; m < 2; m++)
#pragma unroll
    for (int n = 0; n < 4; n++) acc[m][n] = (f32x4){0.f, 0.f, 0.f, 0.f};

  const int srow = lane >> 2;
  const int scol = (lane & 3) * 8;

  auto stage = [&](int buf, int k0) {
#pragma unroll
    for (int c = w; c < BM / 16; c += 4)
      gload_lds16(A + (size_t)(brow + c * 16 + srow) * K + k0 + scol,
                  (char*)As + (size_t)buf * BM * 64 + c * 1024);
#pragma unroll
    for (int c = w; c < BN / 16; c += 4)
      gload_lds16(Bt + (size_t)(bcol + c * 16 + srow) * K + k0 + scol,
                  (char*)Bs + (size_t)buf * BN * 64 + c * 1024);
  };

  stage(0, 0);
  stage(1, 32);

  const int nk = K / 32;
  const int lrow_a = wr * (BM / 2) + (lane & 15);
  const int lrow_b = wc * (BN / 2) + (lane & 15);
  const int lcol   = (lane >> 4) * 8;

  int b0 = 0;
  for (int kt = 0; kt < nk; ++kt) {
    if (kt + 1 < nk) asm volatile("s_waitcnt vmcnt(3)" ::: "memory");
    else             asm volatile("s_waitcnt vmcnt(0)" ::: "memory");
    __builtin_amdgcn_s_barrier();
    __builtin_amdgcn_sched_barrier(0);
    if (kt + 2 < nk) {
      int bn = b0 + 2; if (bn >= 3) bn -= 3;
      stage(bn, (kt + 2) * 32);
    }
    bf16x8 a[2], b[4];
#pragma unroll
    for (int m = 0; m < 2; m++)
      a[m] = *(const bf16x8*)&As[(size_t)b0 * BM * 32 + (lrow_a + m * 16) * 32 + lcol];
#pragma unroll
    for (int n = 0; n < 4; n++)
      b[n] = *(const bf16x8*)&Bs[(size_t)b0 * BN * 32 + (lrow_b + n * 16) * 32 + lcol];
    __builtin_amdgcn_s_setprio(1);
#pragma unroll
    for (int m = 0; m < 2; m++)
#pragma unroll
      for (int n = 0; n < 4; n++)
        acc[m][n] = __builtin_amdgcn_mfma_f32_16x16x32_bf16(a[m], b[n], acc[m][n], 0, 0, 0);
    __builtin_amdgcn_s_setprio(0);
    b0 = (b0 == 2) ? 0 : b0 + 1;
  }

  const int crow0 = brow + wr * (BM / 2);
  const int ccol0 = bcol + wc * (BN / 2);
  const int rsub  = (lane >> 4) * 4;
  const int csub  = lane & 15;
#pragma unroll
  for (int m = 0; m < 2; m++)
#pragma unroll
    for (int n = 0; n < 4; n++) {
      int col = ccol0 + n * 16 + csub;
      float bv = bias[col];
#pragma unroll
      for (int qq = 0; qq < 4; qq++) {
        int row = crow0 + m * 16 + rsub + qq;
        Cv[(size_t)row * N + col] = acc[m][n][qq] + bv;
      }
    }
}

/* Output projection: 512 blocks, panel-colocating swizzle (64-row panels). */
__global__ __launch_bounds__(256) void gemm_out(const unsigned short* __restrict__ ws,
                                                const float* __restrict__ bo,
                                                float* __restrict__ out) {
  __shared__ unsigned short As[3 * 64 * 32];
  __shared__ unsigned short Bs[3 * 128 * 32];
  const int i  = blockIdx.x;        /* 0..511 */
  const int x  = i & 7;
  const int r  = i >> 3;            /* 0..63 */
  const int pm = r >> 3;            /* 0..7 */
  const int bx = r & 7;
  const int by = x * 8 + pm;        /* 0..63 */
  gemm_out_body(As, Bs,
                ws + OFF_CC, ws + OFF_WO, bo, out,
                DM, DM, by * 64, bx * 128);
}

/* ---------------- flash attention (R12 structure, measured 45.4us, UNCHANGED) -------
 * grid: 512 flat (XCD-swizzled). block: 512 = 8 waves in 2 split-K groups of 4.
 * Each group has its own double-buffered gload_lds K/V stream (4 x 16 KB).
 * Wave owns 32 q-rows (q = lane&31). S^T/O^T via 32x32x16 MFMA; P in registers via
 * cvt_pk + permlane32_swap; l accumulated in VALU f32. No-max softmax
 * (P = exp2(s), shift-invariant, bounded scores) -> split combine exact;
 * group B spills (O,l) to LDS scratch, group A adds and writes concat. */
__global__ __launch_bounds__(512, 4) void flash_attn(unsigned short* ws) {
  __shared__ __align__(16) unsigned char smem[65536];   /* 4 x (K 8KB | V 8KB) + f32 scratch */

  const int tid  = threadIdx.x;
  const int lane = tid & 63;
  const int w    = tid >> 6;        /* 0..7 */
  const int s    = w >> 2;          /* k-split group: 0 or 1 */
  const int wsub = w & 3;           /* wave within group -> q-subtile */
  const int q    = lane & 31;
  const int hi   = lane >> 5;
  const int swq  = q & 7;
  const int bid  = blockIdx.x;      /* 0..511 */
  const int swzb = (bid & 7) * 64 + (bid >> 3);   /* XCD-contiguous remap */
  const int qblk = swzb & 15;       /* 0..15, 128 q-rows each */
  const int bh   = swzb >> 4;       /* 0..31 */
  const int b    = bh >> 4, h = bh & 15;

  const unsigned short* Qp = ws + OFF_QP;
  const unsigned short* Kp = ws + OFF_KP;
  const unsigned short* Vp = ws + OFF_VP;
  unsigned short* CC = ws + OFF_CC;

  const unsigned short* Kg = Kp + (size_t)(b * SEQ) * DM + h * 64;          /* +row*DM */
  const unsigned short* Vg = Vp + (size_t)(h * 64) * MR + (size_t)b * SEQ;  /* +row*MR */

  /* Q B-fragments (col=q, k=hi*8+i within 16-d chunk c), prescaled by QSCALE */
  bf16x8 bqf[4];
  {
    const unsigned short* qrow =
        Qp + (size_t)(b * SEQ + qblk * 128 + wsub * 32 + q) * DM + h * 64;
#pragma unroll
    for (int c = 0; c < 4; c++)
      bqf[c] = *(const bf16x8*)(qrow + c * 16 + hi * 8);
  }

  f32x16 o_acc[2];
#pragma unroll
  for (int dt = 0; dt < 2; dt++)
#pragma unroll
    for (int r = 0; r < 16; r++) o_acc[dt][r] = 0.f;
  float l_run = 0.f;

  /* stage k-tile (s*16 + t) into this group's buffer `buf`; 4 waves of the group split it */
  auto stage = [&](int buf, int t) {
    const unsigned short* Kt = Kg + (size_t)(s * 16 + t) * 64 * DM;
    const unsigned short* Vt = Vg + (s * 16 + t) * 64;
    char* base = (char*)smem + (size_t)(s * 2 + buf) * 16384;
#pragma unroll
    for (int i = 0; i < 2; i++) {
      int slot = wsub * 128 + i * 64 + lane;   /* 16B slot 0..511 */
      int srow = slot >> 3;                    /* 0..63 */
      int gch  = (slot & 7) ^ (srow & 7);      /* inverse swizzle on global source */
      gload_lds16(Kt + (size_t)srow * DM + gch * 8, base + slot * 16);
      gload_lds16(Vt + (size_t)srow * MR + gch * 8, base + 8192 + slot * 16);
    }
  };

  stage(0, 0);

  for (int t = 0; t < 16; ++t) {
    int buf = t & 1;
    __syncthreads();   /* stage(t) drained (own-wave vmcnt) + all waves arrived */
    if (t + 1 < 16) stage(buf ^ 1, t + 1);
    const unsigned short* Kb = (const unsigned short*)(smem + (size_t)(s * 2 + buf) * 16384);
    const unsigned short* Vb = Kb + 4096;

    /* ---- S^T[64k][32q] = K · Q^T (log2-domain) ---- */
    f32x16 st0, st1;
#pragma unroll
    for (int r = 0; r < 16; r++) { st0[r] = 0.f; st1[r] = 0.f; }
    __builtin_amdgcn_s_setprio(1);
#pragma unroll
    for (int c = 0; c < 4; c++) {
      int ch = (((c << 1) | hi) ^ swq) << 3;
      bf16x8 ak0 = *(const bf16x8*)&Kb[q * 64 + ch];
      bf16x8 ak1 = *(const bf16x8*)&Kb[(32 + q) * 64 + ch];
      st0 = __builtin_amdgcn_mfma_f32_32x32x16_bf16(ak0, bqf[c], st0, 0, 0, 0);
      st1 = __builtin_amdgcn_mfma_f32_32x32x16_bf16(ak1, bqf[c], st1, 0, 0, 0);
    }
    __builtin_amdgcn_s_setprio(0);

    /* ---- P = exp2(S), packed to bf16 pairs; l accumulates in f32 ---- */
    unsigned int pk0[8], pk1[8];
    float lt = 0.f;
#pragma unroll
    for (int p = 0; p < 8; p++) {
      float a0 = __builtin_amdgcn_exp2f(st0[2 * p]);
      float a1 = __builtin_amdgcn_exp2f(st0[2 * p + 1]);
      float b0 = __builtin_amdgcn_exp2f(st1[2 * p]);
      float b1 = __builtin_amdgcn_exp2f(st1[2 * p + 1]);
      lt += (a0 + a1) + (b0 + b1);
      pk0[p] = cvtpk_bf16(a0, a1);
      pk1[p] = cvtpk_bf16(b0, b1);
    }
    l_run += lt;

    /* ---- redistribute hi-halves: pk[0..3] / pk[4..7] become PV B-frags ---- */
    plane32_swap(pk0[0], pk0[2]); plane32_swap(pk0[1], pk0[3]);
    plane32_swap(pk0[4], pk0[6]); plane32_swap(pk0[5], pk0[7]);
    plane32_swap(pk1[0], pk1[2]); plane32_swap(pk1[1], pk1[3]);
    plane32_swap(pk1[4], pk1[6]); plane32_swap(pk1[5], pk1[7]);

    /* ---- O^T[64d][32q] += V^T · P^T ---- */
    __builtin_amdgcn_s_setprio(1);
#pragma unroll
    for (int t4 = 0; t4 < 4; t4++) {              /* j-chunk of 16 */
      union { unsigned int u[4]; bf16x8 v; } pb;
      const unsigned int* src = (t4 < 2) ? pk0 : pk1;
      pb.u[0] = src[(t4 & 1) * 4 + 0];
      pb.u[1] = src[(t4 & 1) * 4 + 1];
      pb.u[2] = src[(t4 & 1) * 4 + 2];
      pb.u[3] = src[(t4 & 1) * 4 + 3];
      int ch = (((t4 << 1) | hi) ^ swq) << 3;
#pragma unroll
      for (int dt = 0; dt < 2; dt++) {
        bf16x8 av = *(const bf16x8*)&Vb[(dt * 32 + q) * 64 + ch];
        o_acc[dt] = __builtin_amdgcn_mfma_f32_32x32x16_bf16(av, pb.v, o_acc[dt], 0, 0, 0);
      }
    }
    __builtin_amdgcn_s_setprio(0);
  }

  /* ---- combine the two k-splits via LDS scratch (staging buffers are dead) ---- */
  __syncthreads();
  float* scr = (float*)smem;
  float lsum = l_run + __shfl_xor(l_run, 32, 64);   /* combine hi halves */
  if (s == 1) {
    int idx = (wsub * 64 + lane) * 33;              /* stride 33: conflict-free */
#pragma unroll
    for (int dt = 0; dt < 2; dt++)
#pragma unroll
      for (int r = 0; r < 16; r++) scr[idx + dt * 16 + r] = o_acc[dt][r];
    scr[idx + 32] = lsum;
  }
  __syncthreads();
  if (s == 0) {
    int idx = (wsub * 64 + lane) * 33;
#pragma unroll
    for (int dt = 0; dt < 2; dt++)
#pragma unroll
      for (int r = 0; r < 16; r++) o_acc[dt][r] += scr[idx + dt * 16 + r];
    float l = lsum + scr[idx + 32];
    float inv = 1.f / l;

    /* ---- epilogue: O^T[d][q], d = dt*32 + 8*(reg>>2) + 4*hi + (reg&3) ---- */
    int qg = b * SEQ + qblk * 128 + wsub * 32 + q;
    unsigned short* crow = CC + (size_t)qg * DM + h * 64;
#pragma unroll
    for (int dt = 0; dt < 2; dt++)
#pragma unroll
      for (int rq = 0; rq < 4; rq++) {
        ushort4 o;
        o.x = f2bf(o_acc[dt][4 * rq + 0] * inv);
        o.y = f2bf(o_acc[dt][4 * rq + 1] * inv);
        o.z = f2bf(o_acc[dt][4 * rq + 2] * inv);
        o.w = f2bf(o_acc[dt][4 * rq + 3] * inv);
        *(ushort4*)&crow[dt * 32 + rq * 8 + hi * 4] = o;
      }
  }
}

/* ---------------- launch ---------------- */
extern "C" void kernel_launch(void* const* d_in, const int* in_sizes, int n_in,
                              void* d_out, int out_size, void* d_ws, size_t ws_size,
                              hipStream_t stream) {
  const float* q  = (const float*)d_in[0];
  const float* k  = (const float*)d_in[1];
  const float* v  = (const float*)d_in[2];
  const float* Wq = (const float*)d_in[3];
  const float* bq = (const float*)d_in[4];
  const float* Wk = (const float*)d_in[5];
  const float* bk = (const float*)d_in[6];
  const float* Wv = (const float*)d_in[7];
  const float* bv = (const float*)d_in[8];
  const float* Wo = (const float*)d_in[9];
  const float* bo = (const float*)d_in[10];

  unsigned short* ws = (unsigned short*)d_ws;
  float* out = (float*)d_out;

  /* bf16 copies of Wq, Wk, Wo, v (B-side + gemm_out operands): ~8us, BW-bound */
  cvt_all<<<dim3((3 * (W1M / 4) + SMK / 4) / 256), dim3(256), 0, stream>>>(
      Wq, Wk, Wo, v, ws);

  /* Q (prescaled), K, V^T projections: hybrid A-f32-regstaged / B-bf16-gload */
  gemm_qkv<<<dim3(768), dim3(256), 0, stream>>>(q, k, Wv, ws, bq, bk, bv);

  /* attention: 512 blocks x 512 threads, split-K x2 in-block (R9 structure) */
  flash_attn<<<dim3(512), dim3(512), 0, stream>>>(ws);

  /* output projection -> f32 d_out: flat 512 blocks, panel-colocating swizzle */
  gemm_out<<<dim3(512), dim3(256), 0, stream>>>(ws, bo, out);
}